// Round 8
// baseline (268.312 us; speedup 1.0000x reference)
//
#include <hip/hip_runtime.h>
#include <hip/hip_bf16.h>

#define NWIN 4096
#define NH 6
#define NTOK 64
#define CDIM 192
#define SCALE 0.17677669529663687f
#define LOG2E 1.4426950408889634f

typedef __attribute__((ext_vector_type(8))) short short8;
typedef __attribute__((ext_vector_type(4))) short short4v;
typedef __attribute__((ext_vector_type(4))) float f32x4;

#define MFMA32(A, B, C) __builtin_amdgcn_mfma_f32_16x16x32_bf16(A, B, C, 0, 0, 0)
#define MFMA16(A, B, C) __builtin_amdgcn_mfma_f32_16x16x16bf16_1k(A, B, C, 0, 0, 0)

__device__ __forceinline__ short bf(float x) {
  union { __hip_bfloat16 h; short s; } u;
  u.h = __float2bfloat16(x);
  return u.s;
}

__device__ __forceinline__ short8 cvt8v(f32x4 a, f32x4 b) {
  short8 r;
#pragma unroll
  for (int i = 0; i < 4; ++i) { r[i] = bf(a[i]); r[4 + i] = bf(b[i]); }
  return r;
}

// prep: weights -> bf16 (q rows scaled by SCALE*log2e); bias pre-gathered into
// the S^T fragment-coalesced layout biasS2[h][slot(qh,nl,mt)][lane][4] * log2e;
// qkv_b copied with q-part scaled by SCALE*log2e.
__global__ void prep_weights(const float* __restrict__ qkv_w,
                             const float* __restrict__ proj_w,
                             const float* __restrict__ rel_tbl,
                             const float* __restrict__ qkv_b,
                             short* __restrict__ wbuf,
                             float* __restrict__ biasS,
                             float* __restrict__ qkvb2) {
  const int i = blockIdx.x * 256 + threadIdx.x;   // 963*256 = 246528
  if (i < 110592) {
    float v = qkv_w[i];
    if (i < 36864) v *= SCALE * LOG2E;
    wbuf[i] = bf(v);
  } else if (i < 147456) {
    wbuf[i] = bf(proj_w[i - 110592]);
  } else if (i < 245760) {
    const int j = i - 147456;            // [0, 98304) = 6 * 16384
    const int h = j >> 14;
    const int t = j & 16383;
    const int slot = t >> 10;            // (qh*2+nl)*4 + mt
    const int ln = (t >> 2) & 63;
    const int e = t & 3;
    const int qh = slot >> 3, nl = (slot >> 2) & 1, mt = slot & 3;
    const int n = qh * 32 + nl * 16 + (ln & 15);
    const int m = mt * 16 + (ln >> 4) * 4 + e;
    const int idx = ((n >> 3) - (m >> 3) + 7) * 15 + ((n & 7) - (m & 7) + 7);
    biasS[j] = rel_tbl[idx * NH + h] * LOG2E;
  } else {
    const int j = i - 245760;
    if (j < 576) qkvb2[j] = qkv_b[j] * (j < CDIM ? SCALE * LOG2E : 1.0f);
  }
}

#define LDAF(dst, kc) do {                                              \
  _Pragma("unroll")                                                     \
  for (int mt_ = 0; mt_ < 4; ++mt_) {                                   \
    const int r_ = mt_ * 16 + cc;                                       \
    dst[mt_] = *(const short8*)&lds[r_ * CDIM + ((kc) ^ ((r_ & 7) << 3))]; \
  } } while (0)

#define MMQK(q0, q1, k0, k1, af) do {                                   \
  _Pragma("unroll")                                                     \
  for (int mt_ = 0; mt_ < 4; ++mt_) {                                   \
    aq_[0][mt_] = MFMA32(q0, af[mt_], aq_[0][mt_]);                     \
    aq_[1][mt_] = MFMA32(q1, af[mt_], aq_[1][mt_]);                     \
    ak_[0][mt_] = MFMA32(k0, af[mt_], ak_[0][mt_]);                     \
    ak_[1][mt_] = MFMA32(k1, af[mt_], ak_[1][mt_]);                     \
  } } while (0)

#define MMV(v0, v1, af) do {                                            \
  _Pragma("unroll")                                                     \
  for (int mt_ = 0; mt_ < 4; ++mt_) {                                   \
    av_[mt_][0] = MFMA32(af[mt_], v0, av_[mt_][0]);                     \
    av_[mt_][1] = MFMA32(af[mt_], v1, av_[mt_][1]);                     \
  } } while (0)

#define MMP(f0, f1, af) do {                                            \
  _Pragma("unroll")                                                     \
  for (int mt_ = 0; mt_ < 4; ++mt_) {                                   \
    pacc[mt_][0] = MFMA32(f0, af[mt_], pacc[mt_][0]);                   \
    pacc[mt_][1] = MFMA32(f1, af[mt_], pacc[mt_][1]);                   \
  } } while (0)

__global__ __launch_bounds__(384, 3)
void swin_block_kernel(const float* __restrict__ x,
                       const short* __restrict__ wall,   // qkv bf16 | proj bf16
                       const float* __restrict__ qkvb2,  // q-part pre-scaled (incl log2e)
                       const float* __restrict__ proj_b,
                       const float* __restrict__ biasS,  // [6][16][64][4] f32 frag layout
                       float* __restrict__ out) {
  __shared__ __align__(16) short lds[12288];   // 24576 B: x tile, later ao tile

  const int b = blockIdx.x;
  const int tid = threadIdx.x;
  const int w = tid >> 6;        // wave == head
  const int lane = tid & 63;
  const int g = lane >> 4;
  const int cc = lane & 15;

  const float* xp = x + (size_t)b * (NTOK * CDIM);

  // common weight-row offsets (relative to each matrix base)
  const int rq0 = (w * 32 + cc) * CDIM;
  const int rq1 = rq0 + 16 * CDIM;
  const short* wk_ = wall + CDIM * CDIM;
  const short* wv_ = wall + 2 * CDIM * CDIM;
  const short* wp_ = wall + 3 * CDIM * CDIM;

  // ---------------- stage 0: cooperative x -> bf16 LDS (swizzled) ----------------
#pragma unroll
  for (int it = 0; it < 2; ++it) {
    const int flat = (tid + it * 384) * 16;
    const int r = flat / CDIM;
    const int c = flat % CDIM;
    const int X = (r & 7) << 3;
    f32x4 a0 = *(const f32x4*)(xp + flat);
    f32x4 a1 = *(const f32x4*)(xp + flat + 4);
    f32x4 a2 = *(const f32x4*)(xp + flat + 8);
    f32x4 a3 = *(const f32x4*)(xp + flat + 12);
    *(short8*)&lds[r * CDIM + (c ^ X)] = cvt8v(a0, a1);
    *(short8*)&lds[r * CDIM + ((c + 8) ^ X)] = cvt8v(a2, a3);
  }

  // stage-1A prologue weight loads (no LDS dependency -> issue before barrier)
  short8 qA0 = *(const short8*)&wall[rq0 + g * 8];
  short8 qA1 = *(const short8*)&wall[rq1 + g * 8];
  short8 kA0 = *(const short8*)&wk_[rq0 + g * 8];
  short8 kA1 = *(const short8*)&wk_[rq1 + g * 8];
  __syncthreads();

  // ---------------- stage 1 pass A: qT, kT (swapped MFMA), 2-deep pipelined ----------------
  f32x4 aq_[2][4], ak_[2][4];
#pragma unroll
  for (int ft = 0; ft < 2; ++ft)
#pragma unroll
    for (int mt = 0; mt < 4; ++mt) {
      aq_[ft][mt] = (f32x4){0.f, 0.f, 0.f, 0.f};
      ak_[ft][mt] = (f32x4){0.f, 0.f, 0.f, 0.f};
    }

#pragma unroll 1
  for (int ks = 0; ks < 6; ks += 2) {
    const int c1 = (ks + 1) * 32 + g * 8;
    short8 qB0 = *(const short8*)&wall[rq0 + c1];
    short8 qB1 = *(const short8*)&wall[rq1 + c1];
    short8 kB0 = *(const short8*)&wk_[rq0 + c1];
    short8 kB1 = *(const short8*)&wk_[rq1 + c1];
    short8 af0[4];
    LDAF(af0, ks * 32 + g * 8);
    MMQK(qA0, qA1, kA0, kA1, af0);
    if (ks < 4) {
      const int c2 = (ks + 2) * 32 + g * 8;
      qA0 = *(const short8*)&wall[rq0 + c2];
      qA1 = *(const short8*)&wall[rq1 + c2];
      kA0 = *(const short8*)&wk_[rq0 + c2];
      kA1 = *(const short8*)&wk_[rq1 + c2];
    }
    short8 af1[4];
    LDAF(af1, c1);
    MMQK(qB0, qB1, kB0, kB1, af1);
  }

  short4v qf[4][2], kf[4][2];   // [token tile][feature-16 block]
  {
    f32x4 qb[2], kb[2];
#pragma unroll
    for (int ft = 0; ft < 2; ++ft) {
      qb[ft] = *(const f32x4*)&qkvb2[w * 32 + ft * 16 + g * 4];
      kb[ft] = *(const f32x4*)&qkvb2[CDIM + w * 32 + ft * 16 + g * 4];
    }
#pragma unroll
    for (int nt = 0; nt < 4; ++nt)
#pragma unroll
      for (int ft = 0; ft < 2; ++ft)
#pragma unroll
        for (int j = 0; j < 4; ++j) {
          qf[nt][ft][j] = bf(aq_[ft][nt][j] + qb[ft][j]);
          kf[nt][ft][j] = bf(ak_[ft][nt][j] + kb[ft][j]);
        }
  }

  // ---------------- stage 1 pass B: v (normal orientation), pipelined ----------------
  f32x4 av_[4][2];
#pragma unroll
  for (int mt = 0; mt < 4; ++mt)
#pragma unroll
    for (int dt = 0; dt < 2; ++dt)
      av_[mt][dt] = (f32x4){0.f, 0.f, 0.f, 0.f};

  short8 vA0 = *(const short8*)&wv_[rq0 + g * 8];
  short8 vA1 = *(const short8*)&wv_[rq1 + g * 8];
#pragma unroll 1
  for (int ks = 0; ks < 6; ks += 2) {
    const int c1 = (ks + 1) * 32 + g * 8;
    short8 vB0 = *(const short8*)&wv_[rq0 + c1];
    short8 vB1 = *(const short8*)&wv_[rq1 + c1];
    short8 af0[4];
    LDAF(af0, ks * 32 + g * 8);
    MMV(vA0, vA1, af0);
    if (ks < 4) {
      const int c2 = (ks + 2) * 32 + g * 8;
      vA0 = *(const short8*)&wv_[rq0 + c2];
      vA1 = *(const short8*)&wv_[rq1 + c2];
    }
    short8 af1[4];
    LDAF(af1, c1);
    MMV(vB0, vB1, af1);
  }

  short4v vf[2][4];   // [dt feature block][kt token-16 block]
  {
    float vb[2];
    vb[0] = qkvb2[2 * CDIM + w * 32 + cc];
    vb[1] = qkvb2[2 * CDIM + w * 32 + 16 + cc];
#pragma unroll
    for (int dt = 0; dt < 2; ++dt)
#pragma unroll
      for (int kt = 0; kt < 4; ++kt)
#pragma unroll
        for (int j = 0; j < 4; ++j)
          vf[dt][kt][j] = bf(av_[kt][dt][j] + vb[dt]);
  }

  __syncthreads();   // x tile dead everywhere -> lds becomes ao

  // ---------------- stage 2: attention, fully in-register ----------------
  const float* bs = biasS + w * 16384;
#pragma unroll
  for (int qh = 0; qh < 2; ++qh) {
    f32x4 sacc[4][2];
#pragma unroll
    for (int mt = 0; mt < 4; ++mt)
#pragma unroll
      for (int nl = 0; nl < 2; ++nl) {
        // accumulator initialized from frag-coalesced bias (1 KB wave load)
        f32x4 z = *(const f32x4*)&bs[(((qh * 2 + nl) << 2) + mt) * 1024 + lane * 4];
        z = MFMA16(kf[mt][0], qf[qh * 2 + nl][0], z);
        sacc[mt][nl] = MFMA16(kf[mt][1], qf[qh * 2 + nl][1], z);
      }

    // softmax: p = exp2(s) (log2e folded into weights/bias), no max-subtract.
    // exp2f (not inline asm): v_exp_f32 is a TRANS op and needs the compiler's
    // hazard handling -- bare asm caused the round-7 corruption.
    short4v pf[2][4];   // [nl][kt]
#pragma unroll
    for (int nl = 0; nl < 2; ++nl) {
      float sum = 0.f;
#pragma unroll
      for (int mt = 0; mt < 4; ++mt)
#pragma unroll
        for (int e = 0; e < 4; ++e) {
          float p = exp2f(sacc[mt][nl][e]);
          sacc[mt][nl][e] = p;
          sum += p;
        }
      sum += __shfl_xor(sum, 16);
      sum += __shfl_xor(sum, 32);
      const float rinv = __builtin_amdgcn_rcpf(sum);
#pragma unroll
      for (int kt = 0; kt < 4; ++kt)
#pragma unroll
        for (int j = 0; j < 4; ++j)
          pf[nl][kt][j] = bf(sacc[kt][nl][j] * rinv);
    }

    // PV: K = 64 tokens in 4 K=16 steps
    f32x4 oacc[2][2];
#pragma unroll
    for (int nl = 0; nl < 2; ++nl)
#pragma unroll
      for (int dt = 0; dt < 2; ++dt) {
        f32x4 z = (f32x4){0.f, 0.f, 0.f, 0.f};
#pragma unroll
        for (int kt = 0; kt < 4; ++kt)
          z = MFMA16(pf[nl][kt], vf[dt][kt], z);
        oacc[nl][dt] = z;
      }

#pragma unroll
    for (int nl = 0; nl < 2; ++nl)
#pragma unroll
      for (int dt = 0; dt < 2; ++dt)
#pragma unroll
        for (int e = 0; e < 4; ++e) {
          const int r = qh * 32 + nl * 16 + g * 4 + e;
          const int c = w * 32 + dt * 16 + cc;
          lds[r * CDIM + (c ^ ((r & 7) << 3))] = bf(oacc[nl][dt][e]);
        }
  }

  // stage-3 prologue weight loads (no dependency on ao LDS) before the barrier
  short8 pA0 = *(const short8*)&wp_[rq0 + g * 8];
  short8 pA1 = *(const short8*)&wp_[rq1 + g * 8];
  __syncthreads();

  // ---------------- stage 3: output projection (SWAPPED), pipelined ----------------
  // pacc[mt][jt]: row g*4+e = feature w*32+jt*16+g*4+e, col cc = token mt*16+cc
  f32x4 pacc[4][2];
#pragma unroll
  for (int mt = 0; mt < 4; ++mt)
#pragma unroll
    for (int jt = 0; jt < 2; ++jt)
      pacc[mt][jt] = (f32x4){0.f, 0.f, 0.f, 0.f};

#pragma unroll 1
  for (int ks = 0; ks < 6; ks += 2) {
    const int c1 = (ks + 1) * 32 + g * 8;
    short8 pB0 = *(const short8*)&wp_[rq0 + c1];
    short8 pB1 = *(const short8*)&wp_[rq1 + c1];
    short8 af0[4];
    LDAF(af0, ks * 32 + g * 8);
    MMP(pA0, pA1, af0);
    if (ks < 4) {
      const int c2 = (ks + 2) * 32 + g * 8;
      pA0 = *(const short8*)&wp_[rq0 + c2];
      pA1 = *(const short8*)&wp_[rq1 + c2];
    }
    short8 af1[4];
    LDAF(af1, c1);
    MMP(pB0, pB1, af1);
  }

  // ---------------- epilogue: coalesced f32x4 stores ----------------
  float* op = out + (size_t)b * (NTOK * CDIM);
  f32x4 pbv[2];
  pbv[0] = *(const f32x4*)&proj_b[w * 32 + g * 4];
  pbv[1] = *(const f32x4*)&proj_b[w * 32 + 16 + g * 4];
#pragma unroll
  for (int mt = 0; mt < 4; ++mt)
#pragma unroll
    for (int jt = 0; jt < 2; ++jt) {
      f32x4 v = pacc[mt][jt] + pbv[jt];
      *(f32x4*)&op[(mt * 16 + cc) * CDIM + w * 32 + jt * 16 + g * 4] = v;
    }
}

extern "C" void kernel_launch(void* const* d_in, const int* in_sizes, int n_in,
                              void* d_out, int out_size, void* d_ws, size_t ws_size,
                              hipStream_t stream) {
  const float* x       = (const float*)d_in[0];
  const float* qkv_w   = (const float*)d_in[1];
  const float* qkv_b   = (const float*)d_in[2];
  const float* proj_w  = (const float*)d_in[3];
  const float* proj_b  = (const float*)d_in[4];
  const float* rel_tbl = (const float*)d_in[5];
  float* out = (float*)d_out;

  short* wbuf  = (short*)d_ws;                    // 147456 shorts = 294912 B
  float* biasS = (float*)(wbuf + 147456);         // 98304 floats = 393216 B
  float* qkvb2 = biasS + 98304;                   // 576 floats

  prep_weights<<<963, 256, 0, stream>>>(qkv_w, proj_w, rel_tbl, qkv_b,
                                        wbuf, biasS, qkvb2);
  swin_block_kernel<<<NWIN, 384, 0, stream>>>(x, wbuf, qkvb2, proj_b, biasS, out);
}